// Round 7
// baseline (3227.617 us; speedup 1.0000x reference)
//
#include <hip/hip_runtime.h>
#include <hip/hip_fp16.h>
#include <stdint.h>

// TBRNN: x_{t+1} = x + 0.05*n_t + 0.2*(-x + rec(r) + inp_t), r = tanh(x)
// rec[b,i] = sum_{j,k} r[b,j] * w_hh[i,j,k] * r[b,k];  B=16, T=512, I=8, H=256
//
// Round 7 = Round 5 proven skeleton (two LDS barriers, single r_lds, no flag
// handshake) + TWO independent poller teams per chunk:
//   team A (waves 2-3): 1 chunk (64B) per thread, fused asm 4xdwordx4+vmcnt(0)
//   team B (wave 1):    2 chunks (128B) per thread, fused asm 8xdwordx4+vmcnt(0),
//                       phase-offset by s_sleep -> effective sampling period ~RTT/2.
// Both teams write IDENTICAL dwords to the same LDS slots (published data is
// unique per slot) -> benign. All load+waitcnt pairs live in ONE asm statement
// (the R6 failure was in-flight load registers crossing asm-statement
// boundaries, which the compiler may copy before completion).

#define NOISE_STD 0.05f
#define TAU 0.2f

typedef _Float16 f16x8 __attribute__((ext_vector_type(8)));
typedef float f32x4 __attribute__((ext_vector_type(4)));
typedef unsigned int u32x4 __attribute__((ext_vector_type(4)));

__device__ __forceinline__ float fast_tanh(float x){
  float cx = fminf(fmaxf(x, -10.f), 10.f);
  float e = __expf(2.f*cx);
  return 1.f - 2.f*__builtin_amdgcn_rcpf(e + 1.f);
}

// LDS-only block barrier: does NOT drain vmcnt (global stores stay in flight).
__device__ __forceinline__ void block_sync_lds(){
  asm volatile("s_waitcnt lgkmcnt(0)\n\ts_barrier" ::: "memory");
}

__device__ __forceinline__ bool has_sent(u32x4 d){
  return (((d.x & 0xFFFFu)==0xFFFFu) || ((d.x>>16)==0xFFFFu) ||
          ((d.y & 0xFFFFu)==0xFFFFu) || ((d.y>>16)==0xFFFFu) ||
          ((d.z & 0xFFFFu)==0xFFFFu) || ((d.z>>16)==0xFFFFu) ||
          ((d.w & 0xFFFFu)==0xFFFFu) || ((d.w>>16)==0xFFFFu));
}

// ---- pre2[h][t][b] = NOISE_STD*noise + TAU*(u@w_in^T + b_in); + sentinel fill ----
__global__ void pre_kernel(const float* __restrict__ u, const float* __restrict__ noise,
                           const float* __restrict__ w_in_w, const float* __restrict__ w_in_b,
                           float* __restrict__ pre2, unsigned* __restrict__ sent){
  if (threadIdx.x < 128) sent[blockIdx.x*128 + threadIdx.x] = 0xFFFFFFFFu;  // 4 MiB rG
  int F = blockIdx.x*256 + threadIdx.x;      // < 2097152, enumerated [t][h][b]
  int b = F & 15; int h = (F>>4) & 255; int t = F >> 12;
  const float* up = u + (b*512 + t)*8;
  const float* wp = w_in_w + h*8;
  float s = w_in_b[h];
  #pragma unroll
  for (int i = 0; i < 8; ++i) s += up[i]*wp[i];
  pre2[h*8192 + t*16 + b] = NOISE_STD*noise[t*4096 + b*256 + h] + TAU*s;
}

// ---- swizzle w_hh (fp32 [i][j][k]) into fp16 MFMA-B-fragment order ----
// uint4 index = ((i*4 + wv)*32 + jtl*8 + ks)*64 + lane, element e in 0..7
// B[k][n=j]: j = (wv*4+jtl)*16 + (lane&15), k = ks*32 + (lane>>4)*8 + e
__global__ void wsw_kernel(const float* __restrict__ w_hh, __half* __restrict__ wsw){
  int F = blockIdx.x*256 + threadIdx.x;      // < 16777216
  int e = F & 7, lane = (F>>3)&63, ks = (F>>9)&7, jtl = (F>>12)&3, wv = (F>>14)&3, i = F>>16;
  int j = (wv*4 + jtl)*16 + (lane & 15);
  int k = ks*32 + (lane>>4)*8 + e;
  wsw[F] = __float2half(w_hh[(i<<16) | (j<<8) | k]);
}

// ---- persistent recurrence kernel: 256 blocks x 256 threads, cooperative ----
__global__ void __launch_bounds__(256, 1) rnn_kernel(
    const float* __restrict__ x0, const float* __restrict__ pre2, const __half* __restrict__ wsw,
    __half* rG, float* __restrict__ traj, float* __restrict__ xlast)
{
  __shared__ alignas(16) unsigned short r_lds[16*264];  // r[b][k] fp16 bits, stride 264
  __shared__ alignas(16) float pre_lds[8192];           // pre2 slice [t][b_own]
  __shared__ float red[64];

  const int tid = threadIdx.x;
  const int bid = blockIdx.x;                      // = i
  const int wv = tid >> 6, lane = tid & 63;
  const int q = lane >> 4, col = lane & 15;

  // ---- load W[i] fragments into registers once (32KB per wave) ----
  uint4 wreg[4][8];
  {
    const uint4* gw = (const uint4*)wsw + (size_t)(bid*4 + wv)*32*64 + lane;
    #pragma unroll
    for (int jtl = 0; jtl < 4; ++jtl)
      #pragma unroll
      for (int ks = 0; ks < 8; ++ks)
        wreg[jtl][ks] = gw[(jtl*8 + ks)*64];
  }

  // ---- pre slice (512 steps x 16 b = 32KB) -> LDS, fully coalesced ----
  {
    const float4* ps = (const float4*)(pre2 + bid*8192);
    float4* pl = (float4*)pre_lds;
    #pragma unroll
    for (int c = 0; c < 8; ++c) pl[c*256 + tid] = ps[c*256 + tid];
  }

  // ---- init: x slice in registers (lanes 0..15), r_0 in LDS ----
  float xreg = 0.f;
  if (tid < 16) xreg = x0[tid*256 + bid];
  #pragma unroll
  for (int c = 0; c < 16; ++c)
    r_lds[c*264 + tid] = __half_as_ushort(__float2half(fast_tanh(x0[c*256 + tid])));
  __syncthreads();

  #pragma unroll 1
  for (int t = 0; t < 512; ++t){
    // ---- stage 1: tmp[b][j] = sum_k W[i][j][k] r[b][k]  (all waves) ----
    f32x4 acc[4] = {{0.f,0.f,0.f,0.f},{0.f,0.f,0.f,0.f},{0.f,0.f,0.f,0.f},{0.f,0.f,0.f,0.f}};
    #pragma unroll
    for (int ks = 0; ks < 8; ++ks){
      f16x8 A = *(const f16x8*)(r_lds + col*264 + ks*32 + q*8);   // A[b=col][k-frag]
      #pragma unroll
      for (int jtl = 0; jtl < 4; ++jtl){
        union { uint4 u; f16x8 v; } wu; wu.u = wreg[jtl][ks];
        acc[jtl] = __builtin_amdgcn_mfma_f32_16x16x32_f16(A, wu.v, acc[jtl], 0, 0, 0);
      }
    }

    // ---- stage 2: rec[b] partial = sum_j r[b][j]*tmp[b][j] ----
    // D layout: col(j) = lane&15, row(b) = q*4 + reg
    float s[4] = {0.f, 0.f, 0.f, 0.f};
    #pragma unroll
    for (int jtl = 0; jtl < 4; ++jtl){
      int j = (wv*4 + jtl)*16 + col;
      #pragma unroll
      for (int reg = 0; reg < 4; ++reg)
        s[reg] += acc[jtl][reg] * __half2float(__ushort_as_half(r_lds[(q*4 + reg)*264 + j]));
    }
    #pragma unroll
    for (int off = 1; off < 16; off <<= 1){
      #pragma unroll
      for (int reg = 0; reg < 4; ++reg) s[reg] += __shfl_xor(s[reg], off, 64);
    }
    if (col == 0){
      #pragma unroll
      for (int reg = 0; reg < 4; ++reg) red[wv*16 + q*4 + reg] = s[reg];
    }
    block_sync_lds();

    if (tid < 16){
      // ---- owner lanes: update x, publish r fp16 (32B line), traj fp32 ----
      float rec = red[tid] + red[16 + tid] + red[32 + tid] + red[48 + tid];
      float xn = xreg + TAU*(rec - xreg) + pre_lds[t*16 + tid];
      xreg = xn;
      unsigned rv = (unsigned)__half_as_ushort(__float2half(fast_tanh(xn)));
      asm volatile("global_store_short %0, %1, off sc0 sc1"
                   :: "v"(rG + (size_t)t*4096 + bid*16 + tid), "v"(rv) : "memory");
      traj[(size_t)tid*131072 + t*256 + bid] = xn;   // fp32, fire-and-forget
    } else if (tid >= 128 && t < 511){
      // ---- team A (waves 2-3): 1 chunk/thread, fused load+wait asm ----
      const int p = tid - 128;                        // 0..127
      const __half* cp = rG + (size_t)t*4096 + p*32;  // 64B: i=2p,2p+1 x b=0..15
      u32x4 d0, d1, d2, d3;
      __builtin_amdgcn_s_sleep(2);                    // skip the guaranteed-miss sweep
      for (;;){
        asm volatile("global_load_dwordx4 %0, %4, off sc0 sc1\n\t"
                     "global_load_dwordx4 %1, %4, off offset:16 sc0 sc1\n\t"
                     "global_load_dwordx4 %2, %4, off offset:32 sc0 sc1\n\t"
                     "global_load_dwordx4 %3, %4, off offset:48 sc0 sc1\n\t"
                     "s_waitcnt vmcnt(0)"
                     : "=&v"(d0), "=&v"(d1), "=&v"(d2), "=&v"(d3)
                     : "v"(cp) : "memory");
        if (!(has_sent(d0) || has_sent(d1) || has_sent(d2) || has_sent(d3))) break;
      }
      union { u32x4 v[2]; unsigned short h[16]; } U0, U1;
      U0.v[0] = d0; U0.v[1] = d1; U1.v[0] = d2; U1.v[1] = d3;
      unsigned* wl = (unsigned*)r_lds;                // r_lds[b][i], dword column p
      #pragma unroll
      for (int b = 0; b < 16; ++b)
        wl[b*132 + p] = (unsigned)U0.h[b] | ((unsigned)U1.h[b] << 16);
    } else if (tid >= 64 && tid < 128 && t < 511){
      // ---- team B (wave 1): 2 chunks/thread, phase-offset by ~RTT/2 ----
      const int m = tid - 64;                         // 0..63, i = 4m..4m+3
      const __half* cp = rG + (size_t)t*4096 + m*64;  // 128B
      u32x4 e0,e1,e2,e3,e4,e5,e6,e7;
      __builtin_amdgcn_s_sleep(12);                   // stagger vs team A
      for (;;){
        asm volatile("global_load_dwordx4 %0, %8, off sc0 sc1\n\t"
                     "global_load_dwordx4 %1, %8, off offset:16 sc0 sc1\n\t"
                     "global_load_dwordx4 %2, %8, off offset:32 sc0 sc1\n\t"
                     "global_load_dwordx4 %3, %8, off offset:48 sc0 sc1\n\t"
                     "global_load_dwordx4 %4, %8, off offset:64 sc0 sc1\n\t"
                     "global_load_dwordx4 %5, %8, off offset:80 sc0 sc1\n\t"
                     "global_load_dwordx4 %6, %8, off offset:96 sc0 sc1\n\t"
                     "global_load_dwordx4 %7, %8, off offset:112 sc0 sc1\n\t"
                     "s_waitcnt vmcnt(0)"
                     : "=&v"(e0), "=&v"(e1), "=&v"(e2), "=&v"(e3),
                       "=&v"(e4), "=&v"(e5), "=&v"(e6), "=&v"(e7)
                     : "v"(cp) : "memory");
        if (!(has_sent(e0) || has_sent(e1) || has_sent(e2) || has_sent(e3) ||
              has_sent(e4) || has_sent(e5) || has_sent(e6) || has_sent(e7))) break;
      }
      union { u32x4 v[2]; unsigned short h[16]; } V0, V1, V2, V3;
      V0.v[0] = e0; V0.v[1] = e1;   // i = 4m
      V1.v[0] = e2; V1.v[1] = e3;   // i = 4m+1
      V2.v[0] = e4; V2.v[1] = e5;   // i = 4m+2
      V3.v[0] = e6; V3.v[1] = e7;   // i = 4m+3
      unsigned* wl = (unsigned*)r_lds;
      #pragma unroll
      for (int b = 0; b < 16; ++b){
        wl[b*132 + 2*m]     = (unsigned)V0.h[b] | ((unsigned)V1.h[b] << 16);
        wl[b*132 + 2*m + 1] = (unsigned)V2.h[b] | ((unsigned)V3.h[b] << 16);
      }
    }
    block_sync_lds();
  }
  if (tid < 16) xlast[tid*256 + bid] = xreg;
}

// ---- out[b][t][o] = sum_h tanh(traj[b][t][h]) * w_out_w[o][h] + w_out_b[o] ----
__global__ void out_kernel(const float* __restrict__ traj, const float* __restrict__ w_out_w,
                           const float* __restrict__ w_out_b, float* __restrict__ out){
  __shared__ float wo[2048];
  int tid = threadIdx.x;
  #pragma unroll
  for (int c = 0; c < 8; ++c) wo[c*256 + tid] = w_out_w[c*256 + tid];
  __syncthreads();
  int wv = tid >> 6, lane = tid & 63;
  int p = blockIdx.x*4 + wv;                 // p = b*512 + t, < 8192
  float4 v = *(const float4*)&traj[(size_t)p*256 + lane*4];
  float th0 = fast_tanh(v.x), th1 = fast_tanh(v.y), th2 = fast_tanh(v.z), th3 = fast_tanh(v.w);
  #pragma unroll
  for (int o = 0; o < 8; ++o){
    const float* w = &wo[o*256 + lane*4];
    float s = th0*w[0] + th1*w[1] + th2*w[2] + th3*w[3];
    #pragma unroll
    for (int off = 32; off > 0; off >>= 1) s += __shfl_xor(s, off, 64);
    if (lane == 0) out[(size_t)p*8 + o] = s + w_out_b[o];
  }
}

extern "C" void kernel_launch(void* const* d_in, const int* in_sizes, int n_in,
                              void* d_out, int out_size, void* d_ws, size_t ws_size,
                              hipStream_t stream){
  const float* u       = (const float*)d_in[0];
  const float* x0      = (const float*)d_in[1];
  const float* noise   = (const float*)d_in[2];
  const float* w_hh    = (const float*)d_in[3];
  const float* w_in_w  = (const float*)d_in[4];
  const float* w_in_b  = (const float*)d_in[5];
  const float* w_out_w = (const float*)d_in[6];
  const float* w_out_b = (const float*)d_in[7];

  float* out   = (float*)d_out;          // [16][512][8]   = 65536
  float* xlast = out + 65536;            // [16][256]      = 4096
  float* traj  = xlast + 4096;           // [16][512][256] = 2097152

  uint8_t* ws = (uint8_t*)d_ws;
  __half* rG   = (__half*)ws;                          // 4 MiB: 512 slots x [i][b] fp16
  float*  pre2 = (float*)(ws + 4194304);               // 8 MiB: [h][t][b]
  __half* wsw  = (__half*)(ws + 4194304 + 8388608);    // 32 MiB swizzled W (fp16)

  pre_kernel<<<8192, 256, 0, stream>>>(u, noise, w_in_w, w_in_b, pre2, (unsigned*)rG);
  wsw_kernel<<<65536, 256, 0, stream>>>(w_hh, wsw);
  {
    void* args[] = {(void*)&x0, (void*)&pre2, (void*)&wsw,
                    (void*)&rG, (void*)&traj, (void*)&xlast};
    hipLaunchCooperativeKernel((const void*)rnn_kernel, dim3(256), dim3(256),
                               args, 0, stream);
  }
  out_kernel<<<2048, 256, 0, stream>>>(traj, w_out_w, w_out_b, out);
}

// Round 8
// 1819.066 us; speedup vs baseline: 1.7743x; 1.7743x over previous
//
#include <hip/hip_runtime.h>
#include <hip/hip_fp16.h>
#include <stdint.h>

// TBRNN: x_{t+1} = x + 0.05*n_t + 0.2*(-x + rec(r) + inp_t), r = tanh(x)
// rec[b,i] = sum_{j,k} r[b,j] * w_hh[i,j,k] * r[b,k];  B=16, T=512, I=8, H=256
//
// Round 8 = Round 5 proven skeleton (single poller team, waves 2-3, fused
// 4xdwordx4+vmcnt asm, sleep-paced) + MALL PREFETCH of slot t+1:
// each sweep issues a 5th 16B sc0sc1 load at the same chunk offset in slot
// t+1 (fills the 128B MALL line from HBM ahead of use), then waits vmcnt(1)
// so the prefetch never gates the sweep. The pf register is only ever written
// by loads (vmcnt FIFO retire -> WAW safe), never read, and drained with
// vmcnt(0) after the loop. All load+wait pairs stay inside ONE asm statement
// (R6 failure mode: in-flight load regs crossing asm-statement boundaries).

#define NOISE_STD 0.05f
#define TAU 0.2f

typedef _Float16 f16x8 __attribute__((ext_vector_type(8)));
typedef float f32x4 __attribute__((ext_vector_type(4)));
typedef unsigned int u32x4 __attribute__((ext_vector_type(4)));

__device__ __forceinline__ float fast_tanh(float x){
  float cx = fminf(fmaxf(x, -10.f), 10.f);
  float e = __expf(2.f*cx);
  return 1.f - 2.f*__builtin_amdgcn_rcpf(e + 1.f);
}

// LDS-only block barrier: does NOT drain vmcnt (global stores stay in flight).
__device__ __forceinline__ void block_sync_lds(){
  asm volatile("s_waitcnt lgkmcnt(0)\n\ts_barrier" ::: "memory");
}

__device__ __forceinline__ bool has_sent(u32x4 d){
  return (((d.x & 0xFFFFu)==0xFFFFu) || ((d.x>>16)==0xFFFFu) ||
          ((d.y & 0xFFFFu)==0xFFFFu) || ((d.y>>16)==0xFFFFu) ||
          ((d.z & 0xFFFFu)==0xFFFFu) || ((d.z>>16)==0xFFFFu) ||
          ((d.w & 0xFFFFu)==0xFFFFu) || ((d.w>>16)==0xFFFFu));
}

// ---- pre2[h][t][b] = NOISE_STD*noise + TAU*(u@w_in^T + b_in); + sentinel fill ----
__global__ void pre_kernel(const float* __restrict__ u, const float* __restrict__ noise,
                           const float* __restrict__ w_in_w, const float* __restrict__ w_in_b,
                           float* __restrict__ pre2, unsigned* __restrict__ sent){
  if (threadIdx.x < 128) sent[blockIdx.x*128 + threadIdx.x] = 0xFFFFFFFFu;  // 4 MiB rG
  int F = blockIdx.x*256 + threadIdx.x;      // < 2097152, enumerated [t][h][b]
  int b = F & 15; int h = (F>>4) & 255; int t = F >> 12;
  const float* up = u + (b*512 + t)*8;
  const float* wp = w_in_w + h*8;
  float s = w_in_b[h];
  #pragma unroll
  for (int i = 0; i < 8; ++i) s += up[i]*wp[i];
  pre2[h*8192 + t*16 + b] = NOISE_STD*noise[t*4096 + b*256 + h] + TAU*s;
}

// ---- swizzle w_hh (fp32 [i][j][k]) into fp16 MFMA-B-fragment order ----
// uint4 index = ((i*4 + wv)*32 + jtl*8 + ks)*64 + lane, element e in 0..7
// B[k][n=j]: j = (wv*4+jtl)*16 + (lane&15), k = ks*32 + (lane>>4)*8 + e
__global__ void wsw_kernel(const float* __restrict__ w_hh, __half* __restrict__ wsw){
  int F = blockIdx.x*256 + threadIdx.x;      // < 16777216
  int e = F & 7, lane = (F>>3)&63, ks = (F>>9)&7, jtl = (F>>12)&3, wv = (F>>14)&3, i = F>>16;
  int j = (wv*4 + jtl)*16 + (lane & 15);
  int k = ks*32 + (lane>>4)*8 + e;
  wsw[F] = __float2half(w_hh[(i<<16) | (j<<8) | k]);
}

// ---- persistent recurrence kernel: 256 blocks x 256 threads, cooperative ----
__global__ void __launch_bounds__(256, 1) rnn_kernel(
    const float* __restrict__ x0, const float* __restrict__ pre2, const __half* __restrict__ wsw,
    __half* rG, float* __restrict__ traj, float* __restrict__ xlast)
{
  __shared__ alignas(16) unsigned short r_lds[16*264];  // r[b][k] fp16 bits, stride 264
  __shared__ alignas(16) float pre_lds[8192];           // pre2 slice [t][b_own]
  __shared__ float red[64];

  const int tid = threadIdx.x;
  const int bid = blockIdx.x;                      // = i
  const int wv = tid >> 6, lane = tid & 63;
  const int q = lane >> 4, col = lane & 15;

  // ---- load W[i] fragments into registers once (32KB per wave) ----
  uint4 wreg[4][8];
  {
    const uint4* gw = (const uint4*)wsw + (size_t)(bid*4 + wv)*32*64 + lane;
    #pragma unroll
    for (int jtl = 0; jtl < 4; ++jtl)
      #pragma unroll
      for (int ks = 0; ks < 8; ++ks)
        wreg[jtl][ks] = gw[(jtl*8 + ks)*64];
  }

  // ---- pre slice (512 steps x 16 b = 32KB) -> LDS, fully coalesced ----
  {
    const float4* ps = (const float4*)(pre2 + bid*8192);
    float4* pl = (float4*)pre_lds;
    #pragma unroll
    for (int c = 0; c < 8; ++c) pl[c*256 + tid] = ps[c*256 + tid];
  }

  // ---- init: x slice in registers (lanes 0..15), r_0 in LDS ----
  float xreg = 0.f;
  if (tid < 16) xreg = x0[tid*256 + bid];
  #pragma unroll
  for (int c = 0; c < 16; ++c)
    r_lds[c*264 + tid] = __half_as_ushort(__float2half(fast_tanh(x0[c*256 + tid])));
  __syncthreads();

  #pragma unroll 1
  for (int t = 0; t < 512; ++t){
    // ---- stage 1: tmp[b][j] = sum_k W[i][j][k] r[b][k]  (all waves) ----
    f32x4 acc[4] = {{0.f,0.f,0.f,0.f},{0.f,0.f,0.f,0.f},{0.f,0.f,0.f,0.f},{0.f,0.f,0.f,0.f}};
    #pragma unroll
    for (int ks = 0; ks < 8; ++ks){
      f16x8 A = *(const f16x8*)(r_lds + col*264 + ks*32 + q*8);   // A[b=col][k-frag]
      #pragma unroll
      for (int jtl = 0; jtl < 4; ++jtl){
        union { uint4 u; f16x8 v; } wu; wu.u = wreg[jtl][ks];
        acc[jtl] = __builtin_amdgcn_mfma_f32_16x16x32_f16(A, wu.v, acc[jtl], 0, 0, 0);
      }
    }

    // ---- stage 2: rec[b] partial = sum_j r[b][j]*tmp[b][j] ----
    // D layout: col(j) = lane&15, row(b) = q*4 + reg
    float s[4] = {0.f, 0.f, 0.f, 0.f};
    #pragma unroll
    for (int jtl = 0; jtl < 4; ++jtl){
      int j = (wv*4 + jtl)*16 + col;
      #pragma unroll
      for (int reg = 0; reg < 4; ++reg)
        s[reg] += acc[jtl][reg] * __half2float(__ushort_as_half(r_lds[(q*4 + reg)*264 + j]));
    }
    #pragma unroll
    for (int off = 1; off < 16; off <<= 1){
      #pragma unroll
      for (int reg = 0; reg < 4; ++reg) s[reg] += __shfl_xor(s[reg], off, 64);
    }
    if (col == 0){
      #pragma unroll
      for (int reg = 0; reg < 4; ++reg) red[wv*16 + q*4 + reg] = s[reg];
    }
    block_sync_lds();

    if (tid < 16){
      // ---- owner lanes: update x, publish r fp16 (32B line), traj fp32 ----
      float rec = red[tid] + red[16 + tid] + red[32 + tid] + red[48 + tid];
      float xn = xreg + TAU*(rec - xreg) + pre_lds[t*16 + tid];
      xreg = xn;
      unsigned rv = (unsigned)__half_as_ushort(__float2half(fast_tanh(xn)));
      asm volatile("global_store_short %0, %1, off sc0 sc1"
                   :: "v"(rG + (size_t)t*4096 + bid*16 + tid), "v"(rv) : "memory");
      traj[(size_t)tid*131072 + t*256 + bid] = xn;   // fp32, fire-and-forget
    } else if (tid >= 128 && t < 511){
      // ---- pollers (waves 2-3): sweep slot t + MALL-prefetch slot t+1 ----
      const int p = tid - 128;                        // 0..127
      const __half* cp = rG + (size_t)t*4096 + p*32;  // 64B: i=2p,2p+1 x b=0..15
      const __half* pp = cp + 4096;                   // same chunk, slot t+1
      u32x4 d0, d1, d2, d3, pf;
      __builtin_amdgcn_s_sleep(4);                    // skip the guaranteed-miss sweep
      for (;;){
        // 4 sweep loads + 1 prefetch; vmcnt(1) retires the 4 oldest (sweep),
        // leaves the prefetch in flight (reg pf is write-only garbage).
        asm volatile("global_load_dwordx4 %0, %5, off sc0 sc1\n\t"
                     "global_load_dwordx4 %1, %5, off offset:16 sc0 sc1\n\t"
                     "global_load_dwordx4 %2, %5, off offset:32 sc0 sc1\n\t"
                     "global_load_dwordx4 %3, %5, off offset:48 sc0 sc1\n\t"
                     "global_load_dwordx4 %4, %6, off sc0 sc1\n\t"
                     "s_waitcnt vmcnt(1)"
                     : "=&v"(d0), "=&v"(d1), "=&v"(d2), "=&v"(d3), "=&v"(pf)
                     : "v"(cp), "v"(pp) : "memory");
        if (!(has_sent(d0) || has_sent(d1) || has_sent(d2) || has_sent(d3))) break;
        __builtin_amdgcn_s_sleep(1);
      }
      asm volatile("s_waitcnt vmcnt(0)" ::: "memory"); // drain prefetch before reg reuse
      union { u32x4 v[2]; unsigned short h[16]; } U0, U1;
      U0.v[0] = d0; U0.v[1] = d1; U1.v[0] = d2; U1.v[1] = d3;
      unsigned* wl = (unsigned*)r_lds;                // r_lds[b][i], dword column p
      #pragma unroll
      for (int b = 0; b < 16; ++b)
        wl[b*132 + p] = (unsigned)U0.h[b] | ((unsigned)U1.h[b] << 16);
    }
    block_sync_lds();
  }
  if (tid < 16) xlast[tid*256 + bid] = xreg;
}

// ---- out[b][t][o] = sum_h tanh(traj[b][t][h]) * w_out_w[o][h] + w_out_b[o] ----
__global__ void out_kernel(const float* __restrict__ traj, const float* __restrict__ w_out_w,
                           const float* __restrict__ w_out_b, float* __restrict__ out){
  __shared__ float wo[2048];
  int tid = threadIdx.x;
  #pragma unroll
  for (int c = 0; c < 8; ++c) wo[c*256 + tid] = w_out_w[c*256 + tid];
  __syncthreads();
  int wv = tid >> 6, lane = tid & 63;
  int p = blockIdx.x*4 + wv;                 // p = b*512 + t, < 8192
  float4 v = *(const float4*)&traj[(size_t)p*256 + lane*4];
  float th0 = fast_tanh(v.x), th1 = fast_tanh(v.y), th2 = fast_tanh(v.z), th3 = fast_tanh(v.w);
  #pragma unroll
  for (int o = 0; o < 8; ++o){
    const float* w = &wo[o*256 + lane*4];
    float s = th0*w[0] + th1*w[1] + th2*w[2] + th3*w[3];
    #pragma unroll
    for (int off = 32; off > 0; off >>= 1) s += __shfl_xor(s, off, 64);
    if (lane == 0) out[(size_t)p*8 + o] = s + w_out_b[o];
  }
}

extern "C" void kernel_launch(void* const* d_in, const int* in_sizes, int n_in,
                              void* d_out, int out_size, void* d_ws, size_t ws_size,
                              hipStream_t stream){
  const float* u       = (const float*)d_in[0];
  const float* x0      = (const float*)d_in[1];
  const float* noise   = (const float*)d_in[2];
  const float* w_hh    = (const float*)d_in[3];
  const float* w_in_w  = (const float*)d_in[4];
  const float* w_in_b  = (const float*)d_in[5];
  const float* w_out_w = (const float*)d_in[6];
  const float* w_out_b = (const float*)d_in[7];

  float* out   = (float*)d_out;          // [16][512][8]   = 65536
  float* xlast = out + 65536;            // [16][256]      = 4096
  float* traj  = xlast + 4096;           // [16][512][256] = 2097152

  uint8_t* ws = (uint8_t*)d_ws;
  __half* rG   = (__half*)ws;                          // 4 MiB: 512 slots x [i][b] fp16
  float*  pre2 = (float*)(ws + 4194304);               // 8 MiB: [h][t][b]
  __half* wsw  = (__half*)(ws + 4194304 + 8388608);    // 32 MiB swizzled W (fp16)

  pre_kernel<<<8192, 256, 0, stream>>>(u, noise, w_in_w, w_in_b, pre2, (unsigned*)rG);
  wsw_kernel<<<65536, 256, 0, stream>>>(w_hh, wsw);
  {
    void* args[] = {(void*)&x0, (void*)&pre2, (void*)&wsw,
                    (void*)&rG, (void*)&traj, (void*)&xlast};
    hipLaunchCooperativeKernel((const void*)rnn_kernel, dim3(256), dim3(256),
                               args, 0, stream);
  }
  out_kernel<<<2048, 256, 0, stream>>>(traj, w_out_w, w_out_b, out);
}